// Round 1
// baseline (520.271 us; speedup 1.0000x reference)
//
#include <hip/hip_runtime.h>
#include <hip/hip_bf16.h>

#define NB   32      // batch
#define H    1024
#define W    1024
#define TS   64      // output tile edge
#define HALO 3
#define TIN  (TS + 2*HALO)   // 70
#define TOPK 200
#define NMS_THRESH 0.1f
#define LBUF_CAP 1024

// ---------------- Phase 1: 7x7 NMS peak detect + compact ----------------
__global__ __launch_bounds__(256) void peak_kernel(
    const float* __restrict__ in,
    unsigned long long* __restrict__ cand,
    int* __restrict__ counts,
    int cap)
{
    __shared__ float tin[TIN][TIN];    // 19.6 KB
    __shared__ float hmax[TIN][TS];    // 17.9 KB
    __shared__ unsigned long long lbuf[LBUF_CAP]; // 8 KB
    __shared__ int lcnt;
    __shared__ int lbase;

    const int img = blockIdx.z;
    const int tx0 = blockIdx.x * TS;
    const int ty0 = blockIdx.y * TS;
    const float* __restrict__ base = in + (size_t)img * H * W;
    const int t = threadIdx.x;

    if (t == 0) lcnt = 0;

    // load 70x70 tile with -1 padding (all real values >= 0)
    for (int i = t; i < TIN * TIN; i += 256) {
        int r = i / TIN, c = i - r * TIN;
        int gy = ty0 + r - HALO, gx = tx0 + c - HALO;
        float v = -1.0f;
        if (gy >= 0 && gy < H && gx >= 0 && gx < W)
            v = base[(size_t)gy * W + gx];
        tin[r][c] = v;
    }
    __syncthreads();

    // horizontal running 7-max: hmax[r][c] = max(tin[r][c..c+6])
    for (int i = t; i < TIN * TS; i += 256) {
        int r = i / TS, c = i - r * TS;
        float m = tin[r][c];
        #pragma unroll
        for (int k = 1; k < 7; k++) m = fmaxf(m, tin[r][c + k]);
        hmax[r][c] = m;
    }
    __syncthreads();

    // vertical 7-max + peak test
    for (int i = t; i < TS * TS; i += 256) {
        int r = i / TS, c = i - r * TS;
        float m = hmax[r][c];
        #pragma unroll
        for (int k = 1; k < 7; k++) m = fmaxf(m, hmax[r + k][c]);
        float center = tin[r + HALO][c + HALO];
        if (center > NMS_THRESH && center == m) {
            unsigned idx = (unsigned)((ty0 + r) * W + (tx0 + c));
            unsigned long long key =
                ((unsigned long long)__float_as_uint(center) << 32) |
                (unsigned long long)(0xFFFFFFFFu - idx);
            int slot = atomicAdd(&lcnt, 1);
            if (slot < LBUF_CAP) {
                lbuf[slot] = key;
            } else {
                int g = atomicAdd(&counts[img], 1);
                if (g < cap) cand[(size_t)img * cap + g] = key;
            }
        }
    }
    __syncthreads();

    int nc = min(lcnt, LBUF_CAP);
    if (t == 0) lbase = atomicAdd(&counts[img], nc);
    __syncthreads();
    for (int i = t; i < nc; i += 256) {
        int g = lbase + i;
        if (g < cap) cand[(size_t)img * cap + g] = lbuf[i];
    }
}

// ---------------- Phase 2: per-image exact top-200 ----------------
// key = (value_bits << 32) | ~idx  -> unique; descending key == descending
// value with ascending-index tie-break (matches jax.lax.top_k).
__global__ __launch_bounds__(256) void topk_kernel(
    const unsigned long long* __restrict__ cand,
    const int* __restrict__ counts,
    float* __restrict__ out,
    int cap)
{
    const int img = blockIdx.x;
    const int t = threadIdx.x;
    __shared__ unsigned hist[256];
    __shared__ unsigned long long sel[256];
    __shared__ int scnt;
    __shared__ unsigned long long s_prefix;
    __shared__ int s_k;

    int n = counts[img];
    if (n > cap) n = cap;
    const unsigned long long* __restrict__ c = cand + (size_t)img * cap;

    unsigned long long T = 0;
    if (n > TOPK) {
        unsigned long long prefix = 0, maskhi = 0;
        int kk = TOPK;
        for (int byte = 7; byte >= 0; byte--) {
            hist[t] = 0;
            __syncthreads();
            const int shift = byte * 8;
            for (int i = t; i < n; i += 256) {
                unsigned long long key = c[i];
                if ((key & maskhi) == prefix)
                    atomicAdd(&hist[(unsigned)(key >> shift) & 0xFFu], 1u);
            }
            __syncthreads();
            if (t == 0) {
                int acc = 0, d = 255;
                for (; d > 0; d--) {
                    int cnt = (int)hist[d];
                    if (acc + cnt >= kk) break;
                    acc += cnt;
                }
                s_prefix = prefix | ((unsigned long long)(unsigned)d << shift);
                s_k = kk - acc;
            }
            __syncthreads();
            prefix = s_prefix;
            kk = s_k;
            maskhi |= (0xFFull << shift);
            __syncthreads();
        }
        T = prefix;   // exact 200th-largest key
    }

    if (t == 0) scnt = 0;
    __syncthreads();
    for (int i = t; i < n; i += 256) {
        unsigned long long key = c[i];
        if (key >= T) {
            int s = atomicAdd(&scnt, 1);
            if (s < 256) sel[s] = key;
        }
    }
    __syncthreads();
    const int m = min(scnt, 256);
    if (t >= m) sel[t] = 0ull;   // pad sorts last (real values > 0.1 -> key high bits nonzero)
    __syncthreads();

    // bitonic sort 256 keys, descending
    for (int k2 = 2; k2 <= 256; k2 <<= 1) {
        for (int j = k2 >> 1; j > 0; j >>= 1) {
            int ixj = t ^ j;
            if (ixj > t) {
                unsigned long long a = sel[t], b = sel[ixj];
                bool descBlock = ((t & k2) == 0);
                bool sw = descBlock ? (a < b) : (a > b);
                if (sw) { sel[t] = b; sel[ixj] = a; }
            }
            __syncthreads();
        }
    }

    // write: coords [NB,TOPK,2] then probs [NB,TOPK], all as fp32
    const int meff = min(m, TOPK);
    if (t < TOPK) {
        float prob = 0.0f;
        unsigned row = 0, col = 0;
        if (t < meff) {
            unsigned long long key = sel[t];
            prob = __uint_as_float((unsigned)(key >> 32));
            unsigned idx = 0xFFFFFFFFu - (unsigned)(key & 0xFFFFFFFFull);
            row = idx >> 10;        // idx / W
            col = idx & (W - 1);    // idx % W
        }
        size_t cbase = (size_t)img * TOPK * 2 + (size_t)t * 2;
        out[cbase + 0] = (float)row;
        out[cbase + 1] = (float)col;
        out[(size_t)NB * TOPK * 2 + (size_t)img * TOPK + t] = prob;
    }
}

extern "C" void kernel_launch(void* const* d_in, const int* in_sizes, int n_in,
                              void* d_out, int out_size, void* d_ws, size_t ws_size,
                              hipStream_t stream) {
    const float* center_map = (const float*)d_in[0];
    float* out = (float*)d_out;

    // workspace layout: [0,256) counters (NB ints), then candidate keys
    int* counts = (int*)d_ws;
    unsigned long long* cand = (unsigned long long*)((char*)d_ws + 256);
    size_t avail = (ws_size > 256) ? (ws_size - 256) : 0;
    int cap = (int)(avail / (NB * sizeof(unsigned long long)));
    if (cap > 32768) cap = 32768;
    if (cap < 1) cap = 1;

    hipMemsetAsync(counts, 0, NB * sizeof(int), stream);

    dim3 gridA(W / TS, H / TS, NB);
    peak_kernel<<<gridA, 256, 0, stream>>>(center_map, cand, counts, cap);

    topk_kernel<<<NB, 256, 0, stream>>>(cand, counts, out, cap);
}

// Round 2
// 274.318 us; speedup vs baseline: 1.8966x; 1.8966x over previous
//
#include <hip/hip_runtime.h>
#include <hip/hip_bf16.h>

#define NB   32      // batch
#define H    1024
#define W    1024
#define TS   64      // output tile edge
#define HALO 3
#define TROWS (TS + 2*HALO)   // 70
#define TCOLS 72              // padded to 72 for alignment / cheap div
#define TOPK 200
#define NMS_THRESH 0.1f
#define HI_THRESH 0.999f      // fast-path split; exactness preserved by fallback
#define LB_HI 128
#define LB_LO 512

typedef unsigned long long ull;

// ---------------- Phase 1: 7x7 NMS peak detect + compact ----------------
__global__ __launch_bounds__(256) void peak_kernel(
    const float* __restrict__ in,
    ull* __restrict__ cand_hi,
    ull* __restrict__ cand_lo,
    int* __restrict__ counts,   // [0..31]=hi, [32..63]=lo
    int cap_hi, int cap_lo)
{
    __shared__ float tin[TROWS][TCOLS];   // 20160 B
    __shared__ float hmax[TROWS][TS];     // 17920 B
    __shared__ ull lb_hi[LB_HI];          // 1 KB
    __shared__ ull lb_lo[LB_LO];          // 4 KB
    __shared__ int lc_hi, lc_lo, lbase_hi, lbase_lo;

    const int img = blockIdx.z;
    const int tx0 = blockIdx.x * TS;
    const int ty0 = blockIdx.y * TS;
    const float* __restrict__ base = in + (size_t)img * H * W;
    const int t = threadIdx.x;

    if (t == 0) { lc_hi = 0; lc_lo = 0; }

    // ---- phase 1: load 70x72 tile, clamped addresses (always issue load,
    // select -1 for OOB) => 20 independent loads per thread, full MLP ----
    float v[20];
    #pragma unroll
    for (int k = 0; k < 20; k++) {
        int i = t + 256 * k;
        int r = i / TCOLS;            // const divide -> mul_hi+shift
        int c = i - r * TCOLS;
        int gy = ty0 + r - HALO;
        int gx = tx0 + c - HALO;
        int cy = min(max(gy, 0), H - 1);
        int cx = min(max(gx, 0), W - 1);
        float val = base[(size_t)cy * W + cx];
        bool inb = (gy == cy) && (gx == cx);
        v[k] = inb ? val : -1.0f;
    }
    #pragma unroll
    for (int k = 0; k < 20; k++) {
        int i = t + 256 * k;
        if (i < TROWS * TCOLS) ((float*)tin)[i] = v[k];
    }
    __syncthreads();

    // ---- phase 2: horizontal 7-max, 4 outputs per item via prefix/suffix ----
    // 70 rows x 16 groups-of-4 = 1120 items
    #pragma unroll
    for (int k = 0; k < 5; k++) {
        int item = t + 256 * k;
        if (item < TROWS * 16) {
            int r = item >> 4;
            int g = item & 15;
            const float* row = &tin[r][g * 4];
            float4 a = *(const float4*)(row);       // e0..e3
            float4 b = *(const float4*)(row + 4);   // e4..e7
            float2 e89 = *(const float2*)(row + 8); // e8,e9
            float s3 = a.w, s2 = fmaxf(a.z, s3), s1 = fmaxf(a.y, s2), s0 = fmaxf(a.x, s1);
            float p0 = b.x, p1 = fmaxf(p0, b.y), p2 = fmaxf(p1, b.z), p3 = fmaxf(p2, b.w);
            float p4 = fmaxf(p3, e89.x), p5 = fmaxf(p4, e89.y);
            float4 o;
            o.x = fmaxf(s0, p2); o.y = fmaxf(s1, p3);
            o.z = fmaxf(s2, p4); o.w = fmaxf(s3, p5);
            *(float4*)&hmax[r][g * 4] = o;
        }
    }
    __syncthreads();

    // ---- phase 3: vertical 7-max (4 rows per item) + peak test ----
    // 16 row-groups x 64 cols = 1024 items = exactly 4 iters
    #pragma unroll
    for (int k = 0; k < 4; k++) {
        int item = t + 256 * k;
        int c  = item & 63;
        int r0 = (item >> 6) * 4;
        float h[10];
        #pragma unroll
        for (int j = 0; j < 10; j++) h[j] = hmax[r0 + j][c];
        float s3 = h[3], s2 = fmaxf(h[2], s3), s1 = fmaxf(h[1], s2), s0 = fmaxf(h[0], s1);
        float p0 = h[4], p1 = fmaxf(p0, h[5]), p2 = fmaxf(p1, h[6]), p3 = fmaxf(p2, h[7]);
        float p4 = fmaxf(p3, h[8]), p5 = fmaxf(p4, h[9]);
        float m[4] = { fmaxf(s0, p2), fmaxf(s1, p3), fmaxf(s2, p4), fmaxf(s3, p5) };
        float ctr[4];
        #pragma unroll
        for (int j = 0; j < 4; j++) ctr[j] = tin[r0 + 3 + j][c + 3];
        #pragma unroll
        for (int j = 0; j < 4; j++) {
            float center = ctr[j];
            if (center > NMS_THRESH && center == m[j]) {
                unsigned gy = (unsigned)(ty0 + r0 + j);
                unsigned gx = (unsigned)(tx0 + c);
                unsigned idx = (gy << 10) | gx;
                ull key = ((ull)__float_as_uint(center) << 32) |
                          (ull)(0xFFFFFFFFu - idx);
                if (center > HI_THRESH) {
                    int s = atomicAdd(&lc_hi, 1);
                    if (s < LB_HI) lb_hi[s] = key;
                    else {
                        int g = atomicAdd(&counts[img], 1);
                        if (g < cap_hi) cand_hi[(size_t)img * cap_hi + g] = key;
                    }
                } else {
                    int s = atomicAdd(&lc_lo, 1);
                    if (s < LB_LO) lb_lo[s] = key;
                    else {
                        int g = atomicAdd(&counts[32 + img], 1);
                        if (g < cap_lo) cand_lo[(size_t)img * cap_lo + g] = key;
                    }
                }
            }
        }
    }
    __syncthreads();

    int nh = min(lc_hi, LB_HI);
    int nl = min(lc_lo, LB_LO);
    if (t == 0) lbase_hi = atomicAdd(&counts[img], nh);
    if (t == 1) lbase_lo = atomicAdd(&counts[32 + img], nl);
    __syncthreads();
    if (t < nh) {
        int g = lbase_hi + t;
        if (g < cap_hi) cand_hi[(size_t)img * cap_hi + g] = lb_hi[t];
    }
    for (int i = t; i < nl; i += 256) {
        int g = lbase_lo + i;
        if (g < cap_lo) cand_lo[(size_t)img * cap_lo + g] = lb_lo[i];
    }
}

// ---------------- Phase 2: per-image exact top-200 ----------------
// key = (value_bits << 32) | ~idx : unique keys; descending key order ==
// descending value with ascending-index tie-break (matches jax.lax.top_k).
// Radix-select over the 32 VALUE bits only (4 byte passes); equal-value
// ties resolved by the final full-key bitonic sort -> still exact.
__global__ __launch_bounds__(256) void topk_kernel(
    const ull* __restrict__ cand_hi,
    const ull* __restrict__ cand_lo,
    const int* __restrict__ counts,
    float* __restrict__ out,
    int cap_hi, int cap_lo)
{
    const int img = blockIdx.x;
    const int t = threadIdx.x;
    __shared__ unsigned hist[256];
    __shared__ unsigned sfx[256];
    __shared__ ull sel[256];
    __shared__ int scnt;
    __shared__ unsigned s_pref;
    __shared__ int s_k;

    int nh = min(counts[img], cap_hi);
    int nl = min(counts[32 + img], cap_lo);
    const bool use_lo = (nh < TOPK);   // hi list alone provably contains top-K iff nh >= K
    const ull* __restrict__ ch = cand_hi + (size_t)img * cap_hi;
    const ull* __restrict__ cl = cand_lo + (size_t)img * cap_lo;
    const int n = use_lo ? nh + nl : nh;

    unsigned T = 0;   // value-bits threshold (200th-largest value)
    if (n > TOPK) {
        unsigned prefix = 0, maskhi = 0;
        int kk = TOPK;
        for (int byte = 3; byte >= 0; byte--) {
            hist[t] = 0;
            __syncthreads();
            const int shift = byte * 8;
            for (int i = t; i < nh; i += 256) {
                unsigned vb = (unsigned)(ch[i] >> 32);
                if ((vb & maskhi) == prefix)
                    atomicAdd(&hist[(vb >> shift) & 0xFFu], 1u);
            }
            if (use_lo) {
                for (int i = t; i < nl; i += 256) {
                    unsigned vb = (unsigned)(cl[i] >> 32);
                    if ((vb & maskhi) == prefix)
                        atomicAdd(&hist[(vb >> shift) & 0xFFu], 1u);
                }
            }
            __syncthreads();
            // parallel inclusive suffix sum of hist -> sfx
            sfx[t] = hist[t];
            __syncthreads();
            for (int off = 1; off < 256; off <<= 1) {
                unsigned u = (t + off < 256) ? sfx[t + off] : 0u;
                __syncthreads();
                sfx[t] += u;
                __syncthreads();
            }
            // largest digit d with suffix count >= kk
            unsigned nxt = (t == 255) ? 0u : sfx[t + 1];
            if (sfx[t] >= (unsigned)kk && nxt < (unsigned)kk) {
                s_pref = prefix | ((unsigned)t << shift);
                s_k = kk - (int)nxt;
            }
            __syncthreads();
            prefix = s_pref;
            kk = s_k;
            maskhi |= (0xFFu << shift);
            __syncthreads();
        }
        T = prefix;
    }

    // collect all keys with value >= T (count < 200 strictly above T, plus
    // the duplicates of T itself; pad-sort picks the exact top-200)
    if (t == 0) scnt = 0;
    __syncthreads();
    for (int i = t; i < nh; i += 256) {
        ull k = ch[i];
        if ((unsigned)(k >> 32) >= T) {
            int s = atomicAdd(&scnt, 1);
            if (s < 256) sel[s] = k;
        }
    }
    if (use_lo) {
        for (int i = t; i < nl; i += 256) {
            ull k = cl[i];
            if ((unsigned)(k >> 32) >= T) {
                int s = atomicAdd(&scnt, 1);
                if (s < 256) sel[s] = k;
            }
        }
    }
    __syncthreads();
    const int m = min(scnt, 256);
    if (t >= m) sel[t] = 0ull;
    __syncthreads();

    // bitonic sort 256 keys, descending
    for (int k2 = 2; k2 <= 256; k2 <<= 1) {
        for (int j = k2 >> 1; j > 0; j >>= 1) {
            int ixj = t ^ j;
            if (ixj > t) {
                ull a = sel[t], b = sel[ixj];
                bool descBlock = ((t & k2) == 0);
                bool sw = descBlock ? (a < b) : (a > b);
                if (sw) { sel[t] = b; sel[ixj] = a; }
            }
            __syncthreads();
        }
    }

    // write: coords [NB,TOPK,2] then probs [NB,TOPK], all fp32
    const int meff = min(m, TOPK);
    if (t < TOPK) {
        float prob = 0.0f;
        unsigned row = 0, col = 0;
        if (t < meff) {
            ull key = sel[t];
            prob = __uint_as_float((unsigned)(key >> 32));
            unsigned idx = 0xFFFFFFFFu - (unsigned)(key & 0xFFFFFFFFull);
            row = idx >> 10;
            col = idx & (W - 1);
        }
        size_t cbase = (size_t)img * TOPK * 2 + (size_t)t * 2;
        out[cbase + 0] = (float)row;
        out[cbase + 1] = (float)col;
        out[(size_t)NB * TOPK * 2 + (size_t)img * TOPK + t] = prob;
    }
}

extern "C" void kernel_launch(void* const* d_in, const int* in_sizes, int n_in,
                              void* d_out, int out_size, void* d_ws, size_t ws_size,
                              hipStream_t stream) {
    const float* center_map = (const float*)d_in[0];
    float* out = (float*)d_out;

    // workspace: [0,512) counters (64 ints), hi lists, lo lists
    int* counts = (int*)d_ws;
    const int cap_hi = 4096;
    ull* cand_hi = (ull*)((char*)d_ws + 512);
    size_t hi_bytes = (size_t)NB * cap_hi * sizeof(ull);   // 1 MB
    ull* cand_lo = (ull*)((char*)d_ws + 512 + hi_bytes);
    size_t avail = (ws_size > 512 + hi_bytes) ? (ws_size - 512 - hi_bytes) : 0;
    int cap_lo = (int)(avail / (NB * sizeof(ull)));
    if (cap_lo > 32768) cap_lo = 32768;
    if (cap_lo < 1) cap_lo = 1;

    hipMemsetAsync(counts, 0, 64 * sizeof(int), stream);

    dim3 gridA(W / TS, H / TS, NB);
    peak_kernel<<<gridA, 256, 0, stream>>>(center_map, cand_hi, cand_lo, counts,
                                           cap_hi, cap_lo);

    topk_kernel<<<NB, 256, 0, stream>>>(cand_hi, cand_lo, counts, out,
                                        cap_hi, cap_lo);
}